// Round 4
// baseline (719.883 us; speedup 1.0000x reference)
//
#include <hip/hip_runtime.h>

#define NUM_TASKS 8
#define NUM_TABLES 16
#define HASH 1000000
#define BATCH 8192
#define NNZ (BATCH * 20)
#define OFF_ROW (BATCH + 1)
#define NPASS 16
#define RANGE (HASH / NPASS)          // 62500 slots -> 8 tasks * 250KB = 2MB window/XCD
#define PARTIAL_BYTES ((size_t)NPASS * NUM_TABLES * BATCH * NUM_TASKS * 4)  // 64 MB

// Grid: bid = ((pass*2 + tp)*2048 + chunk)*8 + xcd   (524288 blocks, 256 thr)
// table = xcd + 8*tp  -> with round-robin bid%8 -> XCD mapping, each XCD works
// one (table, hash-range) at a time: W window 2MB resident in its 4MB L2.
// Wave = one bag; lane = split*8 + task (tasks broadcast idx, splits stride seg).
template <bool USE_WS>
__global__ void pool_pass_kernel(const float* __restrict__ W,       // [8][16][HASH]
                                 const int* __restrict__ offsets,   // [16][8193]
                                 const int* __restrict__ indices,   // [16][NNZ]
                                 float* __restrict__ partial,       // [NPASS][16][8192][8]
                                 float* __restrict__ out)           // [8][8192][16]
{
    int bid = blockIdx.x;
    int x = bid & 7;            // xcd slot
    int r = bid >> 3;
    int c = r & 2047;           // bag chunk (4 bags)
    r >>= 11;
    int tp = r & 1;             // table half
    int p  = r >> 1;            // hash-range pass (slowest -> serialized by dispatch)
    int t  = x + (tp << 3);

    int wave  = threadIdx.x >> 6;
    int lane  = threadIdx.x & 63;
    int task  = lane & 7;
    int split = lane >> 3;
    int b     = (c << 2) + wave;

    const int lo = p * RANGE;
    const int hi = lo + RANGE;

    int start = offsets[t * OFF_ROW + b];
    int end   = offsets[t * OFF_ROW + b + 1];

    const int*   idxp   = indices + (size_t)t * NNZ;
    const float* Wslice = W + ((size_t)task * NUM_TABLES + t) * (size_t)HASH;

    float acc = 0.0f;
    for (int i = start + split; i < end; i += 8) {
        int h = idxp[i];
        if (h >= lo && h < hi) acc += Wslice[h];   // exec-masked: only in-range lanes fetch
    }

    acc += __shfl_xor(acc, 8);
    acc += __shfl_xor(acc, 16);
    acc += __shfl_xor(acc, 32);

    if (split == 0) {
        if (USE_WS) {
            partial[((((size_t)p * NUM_TABLES + t) * BATCH + b) << 3) + task] = acc;
        } else {
            atomicAdd(&out[((size_t)task * BATCH + b) * NUM_TABLES + t], acc);
        }
    }
}

// out[task][b][t] = sum_p partial[p][t][b][task].
// tid = b*8 + task: partial reads perfectly coalesced per (p,t); out written as 4x float4.
__global__ void reduce_kernel(const float* __restrict__ partial, float* __restrict__ out)
{
    int tid  = blockIdx.x * blockDim.x + threadIdx.x;   // 65536 threads
    int task = tid & 7;
    int b    = tid >> 3;

    float s[NUM_TABLES];
#pragma unroll
    for (int t = 0; t < NUM_TABLES; ++t) s[t] = 0.0f;

    for (int p = 0; p < NPASS; ++p) {
#pragma unroll
        for (int t = 0; t < NUM_TABLES; ++t) {
            s[t] += partial[((((size_t)p * NUM_TABLES + t) * BATCH + b) << 3) + task];
        }
    }

    float4* o = (float4*)(out + ((size_t)task * BATCH + b) * NUM_TABLES);
    o[0] = make_float4(s[0],  s[1],  s[2],  s[3]);
    o[1] = make_float4(s[4],  s[5],  s[6],  s[7]);
    o[2] = make_float4(s[8],  s[9],  s[10], s[11]);
    o[3] = make_float4(s[12], s[13], s[14], s[15]);
}

extern "C" void kernel_launch(void* const* d_in, const int* in_sizes, int n_in,
                              void* d_out, int out_size, void* d_ws, size_t ws_size,
                              hipStream_t stream) {
    const float* W       = (const float*)d_in[0];
    const int*   offsets = (const int*)d_in[1];
    const int*   indices = (const int*)d_in[2];
    float*       out     = (float*)d_out;

    const int grid = NPASS * 2 * 2048 * 8;   // 524288 blocks
    const int block = 256;

    if (ws_size >= PARTIAL_BYTES) {
        float* partial = (float*)d_ws;
        pool_pass_kernel<true><<<grid, block, 0, stream>>>(W, offsets, indices, partial, out);
        reduce_kernel<<<(NUM_TASKS * BATCH) / 256, 256, 0, stream>>>(partial, out);
    } else {
        hipMemsetAsync(d_out, 0, (size_t)out_size * sizeof(float), stream);
        pool_pass_kernel<false><<<grid, block, 0, stream>>>(W, offsets, indices, nullptr, out);
    }
}

// Round 5
// 664.945 us; speedup vs baseline: 1.0826x; 1.0826x over previous
//
#include <hip/hip_runtime.h>

#define NUM_TASKS 8
#define NUM_TABLES 16
#define HASH 1000000
#define BATCH 8192
#define NNZ (BATCH * 20)
#define OFF_ROW (BATCH + 1)
#define NPASS 16
#define RANGE (HASH / NPASS)        // 62500 (fits 16 bits)
#define CHUNK 640                   // sort chunk (10 rounds of 64)
#define NCHUNK (NNZ / CHUNK)        // 256
#define SORT_STRIDE (NNZ + 512)     // per-table sorted array, +pad for 32-align buckets
#define GCHUNKS 40                  // gather grid chunks per bucket
#define GWAVES (GCHUNKS * 4)        // 160 waves per bucket

// ws layout
#define WS_HIST 0                                    // [16][16][256] u32 (hist -> exclusive chunk scan, in place)
#define WS_BB   (256 * 1024)                         // [16][16] u32  bucket base (32-aligned cumsum)
#define WS_CNT  (WS_BB + 1024)                       // [16][16] u32  bucket count
#define WS_SORT (1024 * 1024)                        // [16][SORT_STRIDE] u32 packed (bag<<16 | h_lo)
#define WS_NEED (WS_SORT + (size_t)NUM_TABLES * SORT_STRIDE * 4)

// ---------- 1) per-chunk histogram of hash-range buckets ----------
__global__ void hist_kernel(const int* __restrict__ indices, unsigned* __restrict__ hist)
{
    __shared__ int h[4][NPASS];
    int w = threadIdx.x >> 6, lane = threadIdx.x & 63;
    int g = blockIdx.x * 4 + w;            // 4096 chunk-waves
    int t = g >> 8, chunk = g & 255;
    if (lane < NPASS) h[w][lane] = 0;
    __syncthreads();
    const int* ip = indices + (size_t)t * NNZ + chunk * CHUNK;
    for (int r = 0; r < CHUNK / 64; ++r) {
        int k = ip[r * 64 + lane] / RANGE;
        atomicAdd(&h[w][k], 1);
    }
    __syncthreads();
    if (lane < NPASS) hist[((size_t)t * NPASS + lane) * NCHUNK + chunk] = (unsigned)h[w][lane];
}

// ---------- 2) scan: per-(t,k) exclusive chunk scan + 32-aligned bucket bases ----------
__global__ void scan_kernel(unsigned* __restrict__ hist, unsigned* __restrict__ bb, unsigned* __restrict__ cnt)
{
    int t = blockIdx.x, tid = threadIdx.x;
    __shared__ unsigned tot[NPASS];
    if (tid < NPASS) {
        unsigned run = 0;
        unsigned* hp = hist + ((size_t)t * NPASS + tid) * NCHUNK;
        for (int c = 0; c < NCHUNK; ++c) { unsigned v = hp[c]; hp[c] = run; run += v; }
        tot[tid] = run;
        cnt[t * NPASS + tid] = run;
    }
    __syncthreads();
    if (tid == 0) {
        unsigned base = 0;
        for (int k = 0; k < NPASS; ++k) { bb[t * NPASS + k] = base; base += (tot[k] + 31u) & ~31u; }
    }
}

// ---------- 3) stable scatter: pack (bag, h_lo), rank via ballot, write sorted ----------
__global__ void scatter_kernel(const int* __restrict__ indices, const int* __restrict__ offsets,
                               const unsigned* __restrict__ hist, const unsigned* __restrict__ bb,
                               unsigned* __restrict__ sorted)
{
    int w = threadIdx.x >> 6, lane = threadIdx.x & 63;
    int g = blockIdx.x * 4 + w;
    int t = g >> 8, chunk = g & 255;
    unsigned cur = 0;       // lane k (<16) owns bucket k's running cursor for this chunk
    if (lane < NPASS)
        cur = bb[t * NPASS + lane] + hist[((size_t)t * NPASS + lane) * NCHUNK + chunk];
    unsigned long long mlt = (1ull << lane) - 1ull;
    const int* off = offsets + t * OFF_ROW;
    const int* ip  = indices + (size_t)t * NNZ;
    unsigned* sp   = sorted + (size_t)t * SORT_STRIDE;

    for (int r = 0; r < CHUNK / 64; ++r) {
        int i = chunk * CHUNK + r * 64 + lane;
        int raw = ip[i];
        int k   = raw / RANGE;
        int hlo = raw - k * RANGE;
        int lo = 0, hi = BATCH;                 // bag: largest lo with off[lo] <= i
#pragma unroll
        for (int s = 0; s < 13; ++s) {
            int mid = (lo + hi) >> 1;
            if (off[mid] <= i) lo = mid; else hi = mid;
        }
        unsigned packed = ((unsigned)lo << 16) | (unsigned)hlo;
        unsigned pos = 0;
#pragma unroll
        for (int kk = 0; kk < NPASS; ++kk) {
            unsigned long long m = __ballot(k == kk);
            unsigned bc = (unsigned)__shfl((int)cur, kk, 64);
            if (k == kk) pos = bc + (unsigned)__popcll(m & mlt);
            if (lane == kk) cur += (unsigned)__popcll(m);
        }
        sp[pos] = packed;
    }
}

// ---------- 4) dense gather: pass-serialized, XCD-pinned, 4 entries/lane ----------
__global__ void gather_kernel(const float* __restrict__ W, const unsigned* __restrict__ sorted,
                              const unsigned* __restrict__ bb, const unsigned* __restrict__ cnt,
                              float* __restrict__ out)
{
    int bid = blockIdx.x;
    int x = bid & 7;  int q = bid >> 3;
    int chunk = q % GCHUNKS;  q /= GCHUNKS;
    int tp = q & 1;  int p = q >> 1;        // p slowest: hash windows serialized
    int t = x + (tp << 3);                   // table pinned to XCD slot
    int wavei = chunk * 4 + (threadIdx.x >> 6);
    int lane = threadIdx.x & 63;
    int task = lane & 7, slot = lane >> 3;

    unsigned count = cnt[t * NPASS + p];
    unsigned base  = bb[t * NPASS + p];
    unsigned span  = (((count + GWAVES - 1) / GWAVES) + 31u) & ~31u;
    unsigned e0    = (unsigned)wavei * span;
    unsigned eend  = min(e0 + span, count);
    if (e0 >= eend) return;

    const unsigned* sp = sorted + (size_t)t * SORT_STRIDE + base;
    const float* Wt = W + ((size_t)task * NUM_TABLES + t) * HASH + (size_t)p * RANGE;
    float* op = out + (size_t)task * BATCH * NUM_TABLES + t;

    for (unsigned woff = e0; woff < eend; woff += 32) {
        unsigned es = woff + slot * 4u;
        if (es >= eend) continue;
        uint4 pk = *(const uint4*)(sp + es);
        unsigned n = eend - es;                        // valid entries in this quad (>=1)
        int   bg = (int)(pk.x >> 16);
        float s  = Wt[pk.x & 0xFFFFu];
        if (n > 1) {
            int b1 = (int)(pk.y >> 16); float v = Wt[pk.y & 0xFFFFu];
            if (b1 == bg) s += v; else { atomicAdd(op + (size_t)bg * NUM_TABLES, s); bg = b1; s = v; }
        }
        if (n > 2) {
            int b2 = (int)(pk.z >> 16); float v = Wt[pk.z & 0xFFFFu];
            if (b2 == bg) s += v; else { atomicAdd(op + (size_t)bg * NUM_TABLES, s); bg = b2; s = v; }
        }
        if (n > 3) {
            int b3 = (int)(pk.w >> 16); float v = Wt[pk.w & 0xFFFFu];
            if (b3 == bg) s += v; else { atomicAdd(op + (size_t)bg * NUM_TABLES, s); bg = b3; s = v; }
        }
        atomicAdd(op + (size_t)bg * NUM_TABLES, s);
    }
}

// ---------- fallback (round-3 kernel) if ws is too small ----------
__global__ void pool_fallback_kernel(const float* __restrict__ W, const int* __restrict__ offsets,
                                     const int* __restrict__ indices, float* __restrict__ out)
{
    const int block = blockIdx.x;
    const int t        = block >> 11;
    const int bag_base = (block & 2047) << 2;
    const int wave     = threadIdx.x >> 6;
    const int b        = bag_base + wave;
    const int lane     = threadIdx.x & 63;
    const int task     = lane & 7;
    const int split    = lane >> 3;
    const int start = offsets[t * OFF_ROW + b];
    const int end   = offsets[t * OFF_ROW + b + 1];
    const int*   idxp   = indices + (size_t)t * NNZ;
    const float* Wslice = W + ((size_t)task * NUM_TABLES + t) * (size_t)HASH;
    float acc = 0.0f;
    for (int i = start + split; i < end; i += 8) acc += Wslice[idxp[i]];
    acc += __shfl_xor(acc, 8); acc += __shfl_xor(acc, 16); acc += __shfl_xor(acc, 32);
    if (split == 0) out[((size_t)task * BATCH + b) * NUM_TABLES + t] = acc;
}

extern "C" void kernel_launch(void* const* d_in, const int* in_sizes, int n_in,
                              void* d_out, int out_size, void* d_ws, size_t ws_size,
                              hipStream_t stream) {
    const float* W       = (const float*)d_in[0];
    const int*   offsets = (const int*)d_in[1];
    const int*   indices = (const int*)d_in[2];
    float*       out     = (float*)d_out;

    if (ws_size < WS_NEED) {
        pool_fallback_kernel<<<NUM_TABLES * 2048, 256, 0, stream>>>(W, offsets, indices, out);
        return;
    }

    unsigned* hist   = (unsigned*)((char*)d_ws + WS_HIST);
    unsigned* bb     = (unsigned*)((char*)d_ws + WS_BB);
    unsigned* cntb   = (unsigned*)((char*)d_ws + WS_CNT);
    unsigned* sorted = (unsigned*)((char*)d_ws + WS_SORT);

    hipMemsetAsync(d_out, 0, (size_t)out_size * sizeof(float), stream);

    hist_kernel<<<(NUM_TABLES * NCHUNK) / 4, 256, 0, stream>>>(indices, hist);
    scan_kernel<<<NUM_TABLES, 64, 0, stream>>>(hist, bb, cntb);
    scatter_kernel<<<(NUM_TABLES * NCHUNK) / 4, 256, 0, stream>>>(indices, offsets, hist, bb, sorted);
    gather_kernel<<<NPASS * 2 * GCHUNKS * 8, 256, 0, stream>>>(W, sorted, bb, cntb, out);
}

// Round 6
// 342.606 us; speedup vs baseline: 2.1012x; 1.9408x over previous
//
#include <hip/hip_runtime.h>

#define NUM_TASKS 8
#define NUM_TABLES 16
#define HASH 1000000
#define BATCH 8192
#define NNZ (BATCH * 20)
#define OFF_ROW (BATCH + 1)
#define NPASS 16
#define RANGE (HASH / NPASS)        // 62500
#define CHUNK 640
#define NCHUNK (NNZ / CHUNK)        // 256
#define SORT_STRIDE (NNZ + 512)

// ws layout (bytes). hist/bb/cbag live INSIDE the partial region but are dead
// before gather (the only writer of partial) runs — safe aliasing.
#define WS_PART  0ull                                   // [16p][16t][8192b][8task] f32 = 64 MB
#define WS_HIST  0ull                                   // [16t][16k][256c] u32 = 256 KB
#define WS_BB    262144ull                              // [16t][16k] u32
#define WS_CNTB  263168ull                              // [16t][16k] u32
#define WS_CBAG  (1ull << 20)                           // [16t][16k][8192b] u32 = 8 MB
#define PART_BYTES ((size_t)NPASS * NUM_TABLES * BATCH * NUM_TASKS * 4)   // 67,108,864
#define WS_RP    PART_BYTES                             // [16t][16k][8193] u32 = 8.39 MB
#define RP_BYTES ((size_t)NUM_TABLES * NPASS * (BATCH + 1) * 4)
#define WS_SORT  (WS_RP + RP_BYTES)                     // [16t][SORT_STRIDE] u32 = 10.5 MB
#define WS_NEED  (WS_SORT + (size_t)NUM_TABLES * SORT_STRIDE * 4)         // ~86 MB

// ---------- 1) per-chunk histogram of hash-range buckets ----------
__global__ void hist_kernel(const int* __restrict__ indices, unsigned* __restrict__ hist)
{
    __shared__ int h[4][NPASS];
    int w = threadIdx.x >> 6, lane = threadIdx.x & 63;
    int g = blockIdx.x * 4 + w;
    int t = g >> 8, chunk = g & 255;
    if (lane < NPASS) h[w][lane] = 0;
    __syncthreads();
    const int* ip = indices + (size_t)t * NNZ + chunk * CHUNK;
    for (int r = 0; r < CHUNK / 64; ++r) {
        int k = ip[r * 64 + lane] / RANGE;
        atomicAdd(&h[w][k], 1);
    }
    __syncthreads();
    if (lane < NPASS) hist[((size_t)t * NPASS + lane) * NCHUNK + chunk] = (unsigned)h[w][lane];
}

// ---------- 2) scan: per-(t,k) exclusive chunk scan + 32-aligned bucket bases ----------
__global__ void scan_kernel(unsigned* __restrict__ hist, unsigned* __restrict__ bb, unsigned* __restrict__ cnt)
{
    int t = blockIdx.x, tid = threadIdx.x;
    __shared__ unsigned tot[NPASS];
    if (tid < NPASS) {
        unsigned run = 0;
        unsigned* hp = hist + ((size_t)t * NPASS + tid) * NCHUNK;
        for (int c = 0; c < NCHUNK; ++c) { unsigned v = hp[c]; hp[c] = run; run += v; }
        tot[tid] = run;
        cnt[t * NPASS + tid] = run;
    }
    __syncthreads();
    if (tid == 0) {
        unsigned base = 0;
        for (int k = 0; k < NPASS; ++k) { bb[t * NPASS + k] = base; base += (tot[k] + 31u) & ~31u; }
    }
}

// ---------- 3) stable scatter + per-(t,k,bag) counts ----------
__global__ void scatter_kernel(const int* __restrict__ indices, const int* __restrict__ offsets,
                               const unsigned* __restrict__ hist, const unsigned* __restrict__ bb,
                               unsigned* __restrict__ sorted, unsigned* __restrict__ cbag)
{
    int w = threadIdx.x >> 6, lane = threadIdx.x & 63;
    int g = blockIdx.x * 4 + w;
    int t = g >> 8, chunk = g & 255;
    unsigned cur = 0;
    if (lane < NPASS)
        cur = bb[t * NPASS + lane] + hist[((size_t)t * NPASS + lane) * NCHUNK + chunk];
    unsigned long long mlt = (1ull << lane) - 1ull;
    const int* off = offsets + t * OFF_ROW;
    const int* ip  = indices + (size_t)t * NNZ;
    unsigned* sp   = sorted + (size_t)t * SORT_STRIDE;

    for (int r = 0; r < CHUNK / 64; ++r) {
        int i = chunk * CHUNK + r * 64 + lane;
        int raw = ip[i];
        int k   = raw / RANGE;
        int hlo = raw - k * RANGE;
        int lo = 0, hi = BATCH;                 // bag: largest lo with off[lo] <= i
#pragma unroll
        for (int s = 0; s < 13; ++s) {
            int mid = (lo + hi) >> 1;
            if (off[mid] <= i) lo = mid; else hi = mid;
        }
        unsigned pos = 0;
#pragma unroll
        for (int kk = 0; kk < NPASS; ++kk) {
            unsigned long long m = __ballot(k == kk);
            unsigned bc = (unsigned)__shfl((int)cur, kk, 64);
            if (k == kk) pos = bc + (unsigned)__popcll(m & mlt);
            if (lane == kk) cur += (unsigned)__popcll(m);
        }
        sp[pos] = (unsigned)hlo;
        atomicAdd(&cbag[((size_t)t * NPASS + k) * BATCH + lo], 1u);
    }
}

// ---------- 4) rowptr: per-(t,k) exclusive scan of per-bag counts ----------
__global__ void rowptr_kernel(const unsigned* __restrict__ cbag, const unsigned* __restrict__ bb,
                              unsigned* __restrict__ rowptr)
{
    int tk = blockIdx.x;                      // t*16 + k
    const unsigned* c = cbag + (size_t)tk * BATCH;
    unsigned* rp = rowptr + (size_t)tk * (BATCH + 1);
    __shared__ unsigned tsum[256];
    int tid = threadIdx.x;
    unsigned loc[32];
    unsigned s = 0;
#pragma unroll
    for (int e = 0; e < 32; ++e) { loc[e] = c[tid * 32 + e]; s += loc[e]; }
    tsum[tid] = s;
    __syncthreads();
    if (tid == 0) {
        unsigned run = 0;
        for (int j = 0; j < 256; ++j) { unsigned v = tsum[j]; tsum[j] = run; run += v; }
    }
    __syncthreads();
    unsigned run = bb[tk] + tsum[tid];
#pragma unroll
    for (int e = 0; e < 32; ++e) { rp[tid * 32 + e] = run; run += loc[e]; }
    if (tid == 255) rp[BATCH] = run;
}

// ---------- 5) dense atomic-free gather: pass-serialized, XCD-pinned ----------
__global__ void gather_kernel(const float* __restrict__ W, const unsigned* __restrict__ sorted,
                              const unsigned* __restrict__ rowptr, float* __restrict__ partial)
{
    int bid = blockIdx.x;
    int x = bid & 7;  int q = bid >> 3;
    int blk = q & 255;  q >>= 8;
    int tp = q & 1;  int p = q >> 1;          // p slowest: hash windows serialized
    int t = x + (tp << 3);                    // table pinned to XCD slot
    int lane = threadIdx.x & 63;
    int task = lane & 7, slot = lane >> 3;
    int b = ((blk << 2) + (threadIdx.x >> 6)) * 8 + slot;

    const unsigned* rp = rowptr + (size_t)(t * NPASS + p) * (BATCH + 1);
    unsigned s0 = rp[b], s1 = rp[b + 1];
    const unsigned* sp = sorted + (size_t)t * SORT_STRIDE;
    const float* Wt = W + ((size_t)task * NUM_TABLES + t) * HASH + (size_t)p * RANGE;

    float acc = 0.0f;
    for (unsigned u = s0; u < s1; ++u) acc += Wt[sp[u]];

    partial[(((size_t)p * NUM_TABLES + t) * BATCH + b) * 8 + task] = acc;
}

// ---------- 6) reduce 16 passes ----------
__global__ void reduce_kernel(const float* __restrict__ partial, float* __restrict__ out)
{
    int tid  = blockIdx.x * blockDim.x + threadIdx.x;   // 65536 threads
    int task = tid & 7;
    int b    = tid >> 3;

    float s[NUM_TABLES];
#pragma unroll
    for (int t = 0; t < NUM_TABLES; ++t) s[t] = 0.0f;

    for (int p = 0; p < NPASS; ++p) {
#pragma unroll
        for (int t = 0; t < NUM_TABLES; ++t) {
            s[t] += partial[((((size_t)p * NUM_TABLES + t) * BATCH + b) << 3) + task];
        }
    }

    float4* o = (float4*)(out + ((size_t)task * BATCH + b) * NUM_TABLES);
    o[0] = make_float4(s[0],  s[1],  s[2],  s[3]);
    o[1] = make_float4(s[4],  s[5],  s[6],  s[7]);
    o[2] = make_float4(s[8],  s[9],  s[10], s[11]);
    o[3] = make_float4(s[12], s[13], s[14], s[15]);
}

// ---------- fallback (round-3 kernel) if ws is too small ----------
__global__ void pool_fallback_kernel(const float* __restrict__ W, const int* __restrict__ offsets,
                                     const int* __restrict__ indices, float* __restrict__ out)
{
    const int block = blockIdx.x;
    const int t        = block >> 11;
    const int bag_base = (block & 2047) << 2;
    const int wave     = threadIdx.x >> 6;
    const int b        = bag_base + wave;
    const int lane     = threadIdx.x & 63;
    const int task     = lane & 7;
    const int split    = lane >> 3;
    const int start = offsets[t * OFF_ROW + b];
    const int end   = offsets[t * OFF_ROW + b + 1];
    const int*   idxp   = indices + (size_t)t * NNZ;
    const float* Wslice = W + ((size_t)task * NUM_TABLES + t) * (size_t)HASH;
    float acc = 0.0f;
    for (int i = start + split; i < end; i += 8) acc += Wslice[idxp[i]];
    acc += __shfl_xor(acc, 8); acc += __shfl_xor(acc, 16); acc += __shfl_xor(acc, 32);
    if (split == 0) out[((size_t)task * BATCH + b) * NUM_TABLES + t] = acc;
}

extern "C" void kernel_launch(void* const* d_in, const int* in_sizes, int n_in,
                              void* d_out, int out_size, void* d_ws, size_t ws_size,
                              hipStream_t stream) {
    const float* W       = (const float*)d_in[0];
    const int*   offsets = (const int*)d_in[1];
    const int*   indices = (const int*)d_in[2];
    float*       out     = (float*)d_out;

    if (ws_size < WS_NEED) {
        pool_fallback_kernel<<<NUM_TABLES * 2048, 256, 0, stream>>>(W, offsets, indices, out);
        return;
    }

    unsigned* hist    = (unsigned*)((char*)d_ws + WS_HIST);
    unsigned* bb      = (unsigned*)((char*)d_ws + WS_BB);
    unsigned* cntb    = (unsigned*)((char*)d_ws + WS_CNTB);
    unsigned* cbag    = (unsigned*)((char*)d_ws + WS_CBAG);
    unsigned* rowptr  = (unsigned*)((char*)d_ws + WS_RP);
    unsigned* sorted  = (unsigned*)((char*)d_ws + WS_SORT);
    float*    partial = (float*)((char*)d_ws + WS_PART);

    hipMemsetAsync(cbag, 0, (size_t)NUM_TABLES * NPASS * BATCH * 4, stream);

    hist_kernel<<<(NUM_TABLES * NCHUNK) / 4, 256, 0, stream>>>(indices, hist);
    scan_kernel<<<NUM_TABLES, 64, 0, stream>>>(hist, bb, cntb);
    scatter_kernel<<<(NUM_TABLES * NCHUNK) / 4, 256, 0, stream>>>(indices, offsets, hist, bb, sorted, cbag);
    rowptr_kernel<<<NUM_TABLES * NPASS, 256, 0, stream>>>(cbag, bb, rowptr);
    gather_kernel<<<NPASS * 2 * 256 * 8, 256, 0, stream>>>(W, sorted, rowptr, partial);
    reduce_kernel<<<(NUM_TASKS * BATCH) / 256, 256, 0, stream>>>(partial, out);
}

// Round 7
// 340.207 us; speedup vs baseline: 2.1160x; 1.0071x over previous
//
#include <hip/hip_runtime.h>

#define NUM_TASKS 8
#define NUM_TABLES 16
#define HASH 1000000
#define BATCH 8192
#define NNZ (BATCH * 20)
#define OFF_ROW (BATCH + 1)
#define NPASS 16
#define RANGE (HASH / NPASS)        // 62500
#define CHUNK 640
#define NCHUNK (NNZ / CHUNK)        // 256
#define SORT_STRIDE (NNZ + 512)

// ws layout (bytes). hist/bb/cbag live INSIDE the partial region but are dead
// before gather (the only writer of partial) runs — safe aliasing.
#define WS_PART  0ull                                   // [16p][16t][8192b][8task] f32 = 64 MB
#define WS_HIST  0ull                                   // [16t][16k][256c] u32 = 256 KB
#define WS_BB    262144ull                              // [16t][16k] u32
#define WS_CNTB  263168ull                              // [16t][16k] u32
#define WS_CBAG  (1ull << 20)                           // [16t][16k][8192b] u32 = 8 MB
#define PART_BYTES ((size_t)NPASS * NUM_TABLES * BATCH * NUM_TASKS * 4)   // 67,108,864
#define WS_RP    PART_BYTES                             // [16t][16k][8193] u32 = 8.39 MB
#define RP_BYTES ((size_t)NUM_TABLES * NPASS * (BATCH + 1) * 4)
#define WS_SORT  (WS_RP + RP_BYTES)                     // [16t][SORT_STRIDE] u32 = 10.5 MB
#define WS_NEED  (WS_SORT + (size_t)NUM_TABLES * SORT_STRIDE * 4)         // ~86 MB

// ---------- 1) per-chunk histogram + zero cbag (replaces the pathologically
// slow runtime fillBufferAligned: 8 MB memset was showing ~300us at 27 GB/s) ----------
__global__ void hist_kernel(const int* __restrict__ indices, unsigned* __restrict__ hist,
                            uint4* __restrict__ cbag_v)   // 524288 uint4 = 8 MB
{
    // zero 2 uint4 per thread: 1024 blocks * 256 thr * 2 = 524288
    int zt = blockIdx.x * blockDim.x + threadIdx.x;
    uint4 z = make_uint4(0u, 0u, 0u, 0u);
    cbag_v[zt * 2]     = z;
    cbag_v[zt * 2 + 1] = z;

    __shared__ int h[4][NPASS];
    int w = threadIdx.x >> 6, lane = threadIdx.x & 63;
    int g = blockIdx.x * 4 + w;
    int t = g >> 8, chunk = g & 255;
    if (lane < NPASS) h[w][lane] = 0;
    __syncthreads();
    const int* ip = indices + (size_t)t * NNZ + chunk * CHUNK;
    for (int r = 0; r < CHUNK / 64; ++r) {
        int k = ip[r * 64 + lane] / RANGE;
        atomicAdd(&h[w][k], 1);
    }
    __syncthreads();
    if (lane < NPASS) hist[((size_t)t * NPASS + lane) * NCHUNK + chunk] = (unsigned)h[w][lane];
}

// ---------- 2) scan: per-(t,k) exclusive chunk scan + 32-aligned bucket bases ----------
__global__ void scan_kernel(unsigned* __restrict__ hist, unsigned* __restrict__ bb, unsigned* __restrict__ cnt)
{
    int t = blockIdx.x, tid = threadIdx.x;
    __shared__ unsigned tot[NPASS];
    if (tid < NPASS) {
        unsigned run = 0;
        unsigned* hp = hist + ((size_t)t * NPASS + tid) * NCHUNK;
        for (int c = 0; c < NCHUNK; ++c) { unsigned v = hp[c]; hp[c] = run; run += v; }
        tot[tid] = run;
        cnt[t * NPASS + tid] = run;
    }
    __syncthreads();
    if (tid == 0) {
        unsigned base = 0;
        for (int k = 0; k < NPASS; ++k) { bb[t * NPASS + k] = base; base += (tot[k] + 31u) & ~31u; }
    }
}

// ---------- 3) stable scatter + per-(t,k,bag) counts ----------
__global__ void scatter_kernel(const int* __restrict__ indices, const int* __restrict__ offsets,
                               const unsigned* __restrict__ hist, const unsigned* __restrict__ bb,
                               unsigned* __restrict__ sorted, unsigned* __restrict__ cbag)
{
    int w = threadIdx.x >> 6, lane = threadIdx.x & 63;
    int g = blockIdx.x * 4 + w;
    int t = g >> 8, chunk = g & 255;
    unsigned cur = 0;
    if (lane < NPASS)
        cur = bb[t * NPASS + lane] + hist[((size_t)t * NPASS + lane) * NCHUNK + chunk];
    unsigned long long mlt = (1ull << lane) - 1ull;
    const int* off = offsets + t * OFF_ROW;
    const int* ip  = indices + (size_t)t * NNZ;
    unsigned* sp   = sorted + (size_t)t * SORT_STRIDE;

    for (int r = 0; r < CHUNK / 64; ++r) {
        int i = chunk * CHUNK + r * 64 + lane;
        int raw = ip[i];
        int k   = raw / RANGE;
        int hlo = raw - k * RANGE;
        int lo = 0, hi = BATCH;                 // bag: largest lo with off[lo] <= i
#pragma unroll
        for (int s = 0; s < 13; ++s) {
            int mid = (lo + hi) >> 1;
            if (off[mid] <= i) lo = mid; else hi = mid;
        }
        unsigned pos = 0;
#pragma unroll
        for (int kk = 0; kk < NPASS; ++kk) {
            unsigned long long m = __ballot(k == kk);
            unsigned bc = (unsigned)__shfl((int)cur, kk, 64);
            if (k == kk) pos = bc + (unsigned)__popcll(m & mlt);
            if (lane == kk) cur += (unsigned)__popcll(m);
        }
        sp[pos] = (unsigned)hlo;
        atomicAdd(&cbag[((size_t)t * NPASS + k) * BATCH + lo], 1u);
    }
}

// ---------- 4) rowptr: per-(t,k) exclusive scan of per-bag counts ----------
__global__ void rowptr_kernel(const unsigned* __restrict__ cbag, const unsigned* __restrict__ bb,
                              unsigned* __restrict__ rowptr)
{
    int tk = blockIdx.x;                      // t*16 + k
    const unsigned* c = cbag + (size_t)tk * BATCH;
    unsigned* rp = rowptr + (size_t)tk * (BATCH + 1);
    __shared__ unsigned tsum[256];
    int tid = threadIdx.x;
    unsigned loc[32];
    unsigned s = 0;
#pragma unroll
    for (int e = 0; e < 32; ++e) { loc[e] = c[tid * 32 + e]; s += loc[e]; }
    tsum[tid] = s;
    __syncthreads();
    if (tid == 0) {
        unsigned run = 0;
        for (int j = 0; j < 256; ++j) { unsigned v = tsum[j]; tsum[j] = run; run += v; }
    }
    __syncthreads();
    unsigned run = bb[tk] + tsum[tid];
#pragma unroll
    for (int e = 0; e < 32; ++e) { rp[tid * 32 + e] = run; run += loc[e]; }
    if (tid == 255) rp[BATCH] = run;
}

// ---------- 5) dense atomic-free gather: pass-serialized, XCD-pinned ----------
__global__ void gather_kernel(const float* __restrict__ W, const unsigned* __restrict__ sorted,
                              const unsigned* __restrict__ rowptr, float* __restrict__ partial)
{
    int bid = blockIdx.x;
    int x = bid & 7;  int q = bid >> 3;
    int blk = q & 255;  q >>= 8;
    int tp = q & 1;  int p = q >> 1;          // p slowest: hash windows serialized
    int t = x + (tp << 3);                    // table pinned to XCD slot
    int lane = threadIdx.x & 63;
    int task = lane & 7, slot = lane >> 3;
    int b = ((blk << 2) + (threadIdx.x >> 6)) * 8 + slot;

    const unsigned* rp = rowptr + (size_t)(t * NPASS + p) * (BATCH + 1);
    unsigned s0 = rp[b], s1 = rp[b + 1];
    const unsigned* sp = sorted + (size_t)t * SORT_STRIDE;
    const float* Wt = W + ((size_t)task * NUM_TABLES + t) * HASH + (size_t)p * RANGE;

    float acc = 0.0f;
    for (unsigned u = s0; u < s1; ++u) acc += Wt[sp[u]];

    partial[(((size_t)p * NUM_TABLES + t) * BATCH + b) * 8 + task] = acc;
}

// ---------- 6) reduce 16 passes ----------
__global__ void reduce_kernel(const float* __restrict__ partial, float* __restrict__ out)
{
    int tid  = blockIdx.x * blockDim.x + threadIdx.x;   // 65536 threads
    int task = tid & 7;
    int b    = tid >> 3;

    float s[NUM_TABLES];
#pragma unroll
    for (int t = 0; t < NUM_TABLES; ++t) s[t] = 0.0f;

    for (int p = 0; p < NPASS; ++p) {
#pragma unroll
        for (int t = 0; t < NUM_TABLES; ++t) {
            s[t] += partial[((((size_t)p * NUM_TABLES + t) * BATCH + b) << 3) + task];
        }
    }

    float4* o = (float4*)(out + ((size_t)task * BATCH + b) * NUM_TABLES);
    o[0] = make_float4(s[0],  s[1],  s[2],  s[3]);
    o[1] = make_float4(s[4],  s[5],  s[6],  s[7]);
    o[2] = make_float4(s[8],  s[9],  s[10], s[11]);
    o[3] = make_float4(s[12], s[13], s[14], s[15]);
}

// ---------- fallback (round-3 kernel) if ws is too small ----------
__global__ void pool_fallback_kernel(const float* __restrict__ W, const int* __restrict__ offsets,
                                     const int* __restrict__ indices, float* __restrict__ out)
{
    const int block = blockIdx.x;
    const int t        = block >> 11;
    const int bag_base = (block & 2047) << 2;
    const int wave     = threadIdx.x >> 6;
    const int b        = bag_base + wave;
    const int lane     = threadIdx.x & 63;
    const int task     = lane & 7;
    const int split    = lane >> 3;
    const int start = offsets[t * OFF_ROW + b];
    const int end   = offsets[t * OFF_ROW + b + 1];
    const int*   idxp   = indices + (size_t)t * NNZ;
    const float* Wslice = W + ((size_t)task * NUM_TABLES + t) * (size_t)HASH;
    float acc = 0.0f;
    for (int i = start + split; i < end; i += 8) acc += Wslice[idxp[i]];
    acc += __shfl_xor(acc, 8); acc += __shfl_xor(acc, 16); acc += __shfl_xor(acc, 32);
    if (split == 0) out[((size_t)task * BATCH + b) * NUM_TABLES + t] = acc;
}

extern "C" void kernel_launch(void* const* d_in, const int* in_sizes, int n_in,
                              void* d_out, int out_size, void* d_ws, size_t ws_size,
                              hipStream_t stream) {
    const float* W       = (const float*)d_in[0];
    const int*   offsets = (const int*)d_in[1];
    const int*   indices = (const int*)d_in[2];
    float*       out     = (float*)d_out;

    if (ws_size < WS_NEED) {
        pool_fallback_kernel<<<NUM_TABLES * 2048, 256, 0, stream>>>(W, offsets, indices, out);
        return;
    }

    unsigned* hist    = (unsigned*)((char*)d_ws + WS_HIST);
    unsigned* bb      = (unsigned*)((char*)d_ws + WS_BB);
    unsigned* cntb    = (unsigned*)((char*)d_ws + WS_CNTB);
    unsigned* cbag    = (unsigned*)((char*)d_ws + WS_CBAG);
    unsigned* rowptr  = (unsigned*)((char*)d_ws + WS_RP);
    unsigned* sorted  = (unsigned*)((char*)d_ws + WS_SORT);
    float*    partial = (float*)((char*)d_ws + WS_PART);

    hist_kernel<<<(NUM_TABLES * NCHUNK) / 4, 256, 0, stream>>>(indices, hist, (uint4*)cbag);
    scan_kernel<<<NUM_TABLES, 64, 0, stream>>>(hist, bb, cntb);
    scatter_kernel<<<(NUM_TABLES * NCHUNK) / 4, 256, 0, stream>>>(indices, offsets, hist, bb, sorted, cbag);
    rowptr_kernel<<<NUM_TABLES * NPASS, 256, 0, stream>>>(cbag, bb, rowptr);
    gather_kernel<<<NPASS * 2 * 256 * 8, 256, 0, stream>>>(W, sorted, rowptr, partial);
    reduce_kernel<<<(NUM_TASKS * BATCH) / 256, 256, 0, stream>>>(partial, out);
}